// Round 4
// baseline (494.162 us; speedup 1.0000x reference)
//
#include <hip/hip_runtime.h>
#include <math.h>

#define D   128
#define LQ  256
#define KCQ 9
#define BQ  8
#define TQ  4096
#define RISK_DELTA 5e-4
#define WCAP 65536

// ---------------- precompute kernels (weights-only, tiny, all-double) ----------------
__global__ void pk1(const float* __restrict__ wk, const float* __restrict__ wq,
                    const float* __restrict__ ctx_w, const float* __restrict__ bias_w,
                    double* __restrict__ T2, double* __restrict__ u, int* __restrict__ wcnt) {
    int e = threadIdx.x;
    if (blockIdx.x < D) {
        int d = blockIdx.x;
        double acc = 0.0;
        for (int j = 0; j < D; ++j)
            acc += (double)wk[j * D + d] * (double)wq[j * D + e];
        T2[d * D + e] = acc;
    } else if (blockIdx.x == D) {
        double acc = 0.0;
        for (int dd = 0; dd < D; ++dd)
            acc += (double)bias_w[dd] * (double)ctx_w[dd * D + e];
        u[e] = acc;
    } else {
        if (e == 0) *wcnt = 0;
    }
}

__global__ void pk2(const double* __restrict__ T2, const float* __restrict__ ctx_w,
                    const float* __restrict__ conv_w, const float* __restrict__ conv_b,
                    const float* __restrict__ ctx_b,
                    double* __restrict__ g, double* __restrict__ c1) {
    __shared__ double row[D];
    int d = blockIdx.x, e = threadIdx.x;
    double acc = 0.0;
    for (int j = 0; j < D; ++j)
        acc += T2[d * D + j] * (double)ctx_w[j * D + e];
    row[e] = acc;
    __syncthreads();
    if (e < KCQ) {
        double a = 0.0;
        for (int q = 0; q < D; ++q) a += row[q] * (double)conv_w[q * KCQ + e];
        g[e * D + d] = a;           // tap-major: g[k][d]
    } else if (e == KCQ) {
        double a = 0.0;
        for (int q = 0; q < D; ++q) a += row[q] * (double)conv_b[q];
        for (int q = 0; q < D; ++q) a += T2[d * D + q] * (double)ctx_b[q];
        c1[d] = a;
    }
}

__global__ void pk3(const float* __restrict__ lag_embed, const float* __restrict__ val_b,
                    const float* __restrict__ val_w, const float* __restrict__ conv_w,
                    const float* __restrict__ conv_b, const float* __restrict__ ctx_b,
                    const float* __restrict__ bias_w, const float* __restrict__ bias_b,
                    const double* __restrict__ g, const double* __restrict__ c1,
                    const double* __restrict__ u,
                    double* __restrict__ gbT, double* __restrict__ cbv, double* __restrict__ cst) {
    int tid = threadIdx.x;
    if (blockIdx.x < LQ) {
        __shared__ double bl[D];
        int l = blockIdx.x;
        bl[tid] = (double)val_b[tid] + (double)lag_embed[(l + 1) * D + tid];
        __syncthreads();
        if (tid < KCQ) {
            double a = 0.0;
            for (int q = 0; q < D; ++q) a += bl[q] * g[tid * D + q];
            gbT[tid * LQ + l] = a;
        } else if (tid == KCQ) {
            double a = 0.0;
            for (int q = 0; q < D; ++q) a += bl[q] * c1[q];
            cbv[l] = a;
        }
    } else {
        if (tid < KCQ) {
            double a = 0.0, a2 = 0.0;
            for (int q = 0; q < D; ++q) a  += g[tid * D + q] * (double)val_w[q];
            for (int q = 0; q < D; ++q) a2 += u[q] * (double)conv_w[q * KCQ + tid];
            cst[tid]      = a;    // sk[k]
            cst[10 + tid] = a2;   // hk[k]
        } else if (tid == KCQ) {
            double a = 0.0, a2 = 0.0;
            for (int q = 0; q < D; ++q) a  += c1[q] * (double)val_w[q];
            for (int q = 0; q < D; ++q) a2 += u[q] * (double)conv_b[q];
            for (int q = 0; q < D; ++q) a2 += (double)bias_w[q] * (double)ctx_b[q];
            cst[9]  = a;                          // ssc
            cst[19] = a2 + (double)bias_b[0];     // hc (incl. bias_b)
        }
    }
}

// ---------------- main kernel: exact f64 collapsed; near-tie rows deferred ----------
__global__ __launch_bounds__(256, 4) void lag_main(
    const float* __restrict__ x, const double* __restrict__ gbT,
    const double* __restrict__ cbv, const double* __restrict__ cst,
    float* __restrict__ muOut, float* __restrict__ wOut,
    int* __restrict__ wcnt, int* __restrict__ wlist) {
    __shared__ double sgb[KCQ * LQ];
    __shared__ double scb[LQ];
    __shared__ double sc[20];
    int tid = threadIdx.x;
    #pragma unroll
    for (int i = 0; i < KCQ; ++i) sgb[i * LQ + tid] = gbT[i * LQ + tid];
    scb[tid] = cbv[tid];
    if (tid < 20) sc[tid] = cst[tid];
    __syncthreads();

    int wave = tid >> 6, lane = tid & 63;
    int row = blockIdx.x * 4 + wave;
    int b = row >> 12;
    int t = row & (TQ - 1);
    const float* xb = x + b * TQ;

    double xw[KCQ];
    #pragma unroll
    for (int k = 0; k < KCQ; ++k) {
        int idx = t - 8 + k;
        xw[k] = (idx >= 0) ? (double)xb[idx] : 0.0;
    }
    double s = sc[9], bias = sc[19];
    #pragma unroll
    for (int k = 0; k < KCQ; ++k) {
        s    = fma(sc[k],      xw[k], s);
        bias = fma(sc[10 + k], xw[k], bias);
    }

    double xlag[4], lg[4];
    #pragma unroll
    for (int j = 0; j < 4; ++j) {
        int l = lane + 64 * j;
        int idx = t - 1 - l;
        xlag[j] = (idx >= 0) ? (double)xb[idx] : 0.0;
        double acc = scb[l];
        #pragma unroll
        for (int k = 0; k < KCQ; ++k)
            acc = fma(sgb[k * LQ + l], xw[k], acc);
        lg[j] = fma(xlag[j], s, acc);
    }

    // top-9 extraction: v1 (mx), v8 (thr), v9 (risk gap)
    const double NEG_INF = -__builtin_inf();
    double wl0 = lg[0], wl1 = lg[1], wl2 = lg[2], wl3 = lg[3];
    double mx = 0.0, thr = 0.0, v9 = 0.0;
    #pragma unroll
    for (int it = 0; it < 9; ++it) {
        double lm = fmax(fmax(wl0, wl1), fmax(wl2, wl3));
        double m = lm;
        #pragma unroll
        for (int off = 32; off >= 1; off >>= 1)
            m = fmax(m, __shfl_xor(m, off, 64));
        if (it == 0) mx = m;
        if (it == 7) thr = m;
        if (it == 8) v9 = m;
        if (it < 8) {
            unsigned long long ball = __ballot(lm == m);
            int leader = __ffsll(ball) - 1;
            if (lane == leader) {
                if (wl0 == m)      wl0 = NEG_INF;
                else if (wl1 == m) wl1 = NEG_INF;
                else if (wl2 == m) wl2 = NEG_INF;
                else               wl3 = NEG_INF;
            }
        }
    }

    if ((thr - v9) < RISK_DELTA) {
        if (lane == 0) {
            int pos = atomicAdd(wcnt, 1);
            if (pos < WCAP) wlist[pos] = row;
        }
        return;
    }

    double p[4], psum = 0.0, pmu = 0.0;
    #pragma unroll
    for (int j = 0; j < 4; ++j) {
        p[j] = (lg[j] >= thr) ? exp(lg[j] - mx) : 0.0;
        psum += p[j];
        pmu = fma(p[j], xlag[j], pmu);
    }
    #pragma unroll
    for (int off = 32; off >= 1; off >>= 1) {
        psum += __shfl_xor(psum, off, 64);
        pmu  += __shfl_xor(pmu,  off, 64);
    }
    double inv = 1.0 / psum;
    #pragma unroll
    for (int j = 0; j < 4; ++j)
        wOut[(size_t)row * LQ + lane + 64 * j] = (float)(p[j] * inv);
    if (lane == 0) muOut[row] = (float)(pmu * inv + bias);
}

// ---------------- fixer: np-faithful fp32 pipeline (sequential f32 FMA dots) --------
__global__ __launch_bounds__(256) void fixer(
    const float* __restrict__ x, const float* __restrict__ lag_embed,
    const float* __restrict__ val_w, const float* __restrict__ val_b,
    const float* __restrict__ conv_w, const float* __restrict__ conv_b,
    const float* __restrict__ ctx_w, const float* __restrict__ ctx_b,
    const float* __restrict__ wq, const float* __restrict__ wk,
    const float* __restrict__ bias_w, const float* __restrict__ bias_b,
    const int* __restrict__ wcnt, const int* __restrict__ wlist,
    float* __restrict__ muOut, float* __restrict__ wOut) {
    __shared__ float sxw[8][KCQ];
    __shared__ float sctxc[8][D];
    __shared__ float sctxp[8][D];
    __shared__ float sq[8][D];
    __shared__ float sqk[8][D];
    __shared__ float ssv[8];
    __shared__ float sbd[8];
    __shared__ float slog[8][LQ];
    __shared__ int   srow[8];

    int cnt = *wcnt;
    if (cnt > WCAP) cnt = WCAP;
    int ngroups = (cnt + 7) >> 3;
    int tid = threadIdx.x;

    for (int gi = blockIdx.x; gi < ngroups; gi += gridDim.x) {
        if (tid < 8) {
            int idx = gi * 8 + tid;
            if (idx >= cnt) idx = cnt - 1;   // pad with last row (duplicate write is benign)
            srow[tid] = wlist[idx];
        }
        __syncthreads();
        if (tid < 8 * KCQ) {
            int g = tid / KCQ, k = tid % KCQ;
            int row = srow[g]; int b = row >> 12, t = row & (TQ - 1);
            int ii = t - 8 + k;
            sxw[g][k] = (ii >= 0) ? x[b * TQ + ii] : 0.f;
        }
        __syncthreads();

        // stage 1: causal conv — sequential f32 FMA over k, then f32 add of conv_b
        {
            int d = tid & (D - 1), gh = tid >> 7;
            for (int g = gh * 4; g < gh * 4 + 4; ++g) {
                float a = 0.f;
                #pragma unroll
                for (int k = 0; k < KCQ; ++k)
                    a = fmaf(conv_w[d * KCQ + k], sxw[g][k], a);
                sctxc[g][d] = __fadd_rn(a, conv_b[d]);
            }
        }
        __syncthreads();

        // stage 2: ctx_proj — sequential f32 FMA over d, then + ctx_b
        {
            int e = tid & (D - 1), gh = tid >> 7, g0 = gh * 4;
            float a0 = 0.f, a1 = 0.f, a2 = 0.f, a3 = 0.f;
            for (int d2 = 0; d2 < D; ++d2) {
                float wv = ctx_w[e * D + d2];
                a0 = fmaf(wv, sctxc[g0 + 0][d2], a0);
                a1 = fmaf(wv, sctxc[g0 + 1][d2], a1);
                a2 = fmaf(wv, sctxc[g0 + 2][d2], a2);
                a3 = fmaf(wv, sctxc[g0 + 3][d2], a3);
            }
            float cb = ctx_b[e];
            sctxp[g0 + 0][e] = __fadd_rn(a0, cb);
            sctxp[g0 + 1][e] = __fadd_rn(a1, cb);
            sctxp[g0 + 2][e] = __fadd_rn(a2, cb);
            sctxp[g0 + 3][e] = __fadd_rn(a3, cb);
        }
        __syncthreads();

        // stage 3: q = ctx @ wq.T — sequential f32 FMA over e
        {
            int a = tid & (D - 1), gh = tid >> 7, g0 = gh * 4;
            float a0 = 0.f, a1 = 0.f, a2 = 0.f, a3 = 0.f;
            for (int e2 = 0; e2 < D; ++e2) {
                float wv = wq[a * D + e2];
                a0 = fmaf(wv, sctxp[g0 + 0][e2], a0);
                a1 = fmaf(wv, sctxp[g0 + 1][e2], a1);
                a2 = fmaf(wv, sctxp[g0 + 2][e2], a2);
                a3 = fmaf(wv, sctxp[g0 + 3][e2], a3);
            }
            sq[g0 + 0][a] = a0;
            sq[g0 + 1][a] = a1;
            sq[g0 + 2][a] = a2;
            sq[g0 + 3][a] = a3;
        }
        __syncthreads();

        // stage 4: qk = q @ wk — sequential f32 FMA over a
        {
            int d = tid & (D - 1), gh = tid >> 7, g0 = gh * 4;
            float a0 = 0.f, a1 = 0.f, a2 = 0.f, a3 = 0.f;
            for (int a2i = 0; a2i < D; ++a2i) {
                float wv = wk[a2i * D + d];
                a0 = fmaf(wv, sq[g0 + 0][a2i], a0);
                a1 = fmaf(wv, sq[g0 + 1][a2i], a1);
                a2 = fmaf(wv, sq[g0 + 2][a2i], a2);
                a3 = fmaf(wv, sq[g0 + 3][a2i], a3);
            }
            sqk[g0 + 0][d] = a0;
            sqk[g0 + 1][d] = a1;
            sqk[g0 + 2][d] = a2;
            sqk[g0 + 3][d] = a3;
        }
        __syncthreads();

        // s = qk·val_w ; biasdot = ctxp·bias_w — sequential f32 FMA
        if (tid < 8) {
            int g = tid;
            float a = 0.f;
            for (int d2 = 0; d2 < D; ++d2) a = fmaf(sqk[g][d2], val_w[d2], a);
            ssv[g] = a;
        } else if (tid < 16) {
            int g = tid - 8;
            float a = 0.f;
            for (int e2 = 0; e2 < D; ++e2) a = fmaf(sctxp[g][e2], bias_w[e2], a);
            sbd[g] = a;
        }
        __syncthreads();

        // logits: blog[l] = Σ_d f32(val_b+le)·qk[d] sequential f32 FMA;
        // logit = f32(xlag*s) + blog (separate f32 mul/add, like numpy elementwise)
        {
            int l = tid;
            float c0 = 0.f, c1a = 0.f, c2 = 0.f, c3 = 0.f, c4 = 0.f, c5 = 0.f, c6 = 0.f, c7 = 0.f;
            const float* le = lag_embed + (size_t)(l + 1) * D;
            for (int d2 = 0; d2 < D; ++d2) {
                float bd = __fadd_rn(val_b[d2], le[d2]);
                c0 = fmaf(bd, sqk[0][d2], c0);
                c1a = fmaf(bd, sqk[1][d2], c1a);
                c2 = fmaf(bd, sqk[2][d2], c2);
                c3 = fmaf(bd, sqk[3][d2], c3);
                c4 = fmaf(bd, sqk[4][d2], c4);
                c5 = fmaf(bd, sqk[5][d2], c5);
                c6 = fmaf(bd, sqk[6][d2], c6);
                c7 = fmaf(bd, sqk[7][d2], c7);
            }
            float accs[8] = {c0, c1a, c2, c3, c4, c5, c6, c7};
            #pragma unroll
            for (int g = 0; g < 8; ++g) {
                int row = srow[g]; int b = row >> 12, t = row & (TQ - 1);
                int ii = t - 1 - l;
                float xl = (ii >= 0) ? x[b * TQ + ii] : 0.f;
                slog[g][l] = __fadd_rn(__fmul_rn(xl, ssv[g]), accs[g]);
            }
        }
        __syncthreads();

        // per-row f32 top-8 + f32 softmax + writes; wave handles 2 rows
        {
            int wave = tid >> 6, lane = tid & 63;
            for (int gg = wave * 2; gg < wave * 2 + 2; ++gg) {
                float lv0 = slog[gg][lane], lv1 = slog[gg][lane + 64];
                float lv2 = slog[gg][lane + 128], lv3 = slog[gg][lane + 192];
                const float NEG_INF = -__builtin_inff();
                float w0 = lv0, w1 = lv1, w2 = lv2, w3 = lv3;
                float mx = 0.f, thr = 0.f;
                #pragma unroll
                for (int it = 0; it < 8; ++it) {
                    float lm = fmaxf(fmaxf(w0, w1), fmaxf(w2, w3));
                    float m = lm;
                    #pragma unroll
                    for (int off = 32; off >= 1; off >>= 1)
                        m = fmaxf(m, __shfl_xor(m, off, 64));
                    if (it == 0) mx = m;
                    thr = m;
                    if (it < 7) {
                        unsigned long long ball = __ballot(lm == m);
                        int leader = __ffsll(ball) - 1;
                        if (lane == leader) {
                            if (w0 == m)      w0 = NEG_INF;
                            else if (w1 == m) w1 = NEG_INF;
                            else if (w2 == m) w2 = NEG_INF;
                            else              w3 = NEG_INF;
                        }
                    }
                }
                int row = srow[gg]; int b = row >> 12, t = row & (TQ - 1);
                float p[4], xlg[4];
                double ps = 0.0;
                float lvs[4] = {lv0, lv1, lv2, lv3};
                #pragma unroll
                for (int j = 0; j < 4; ++j) {
                    int l = lane + 64 * j;
                    int ii = t - 1 - l;
                    xlg[j] = (ii >= 0) ? x[b * TQ + ii] : 0.f;
                    p[j] = (lvs[j] >= thr) ? (float)exp((double)__fsub_rn(lvs[j], mx)) : 0.f;
                    ps += (double)p[j];
                }
                #pragma unroll
                for (int off = 32; off >= 1; off >>= 1)
                    ps += __shfl_xor(ps, off, 64);
                float psf = (float)ps;
                double mud = 0.0;
                #pragma unroll
                for (int j = 0; j < 4; ++j) {
                    float wv = __fdiv_rn(p[j], psf);
                    wOut[(size_t)row * LQ + lane + 64 * j] = wv;
                    mud += (double)__fmul_rn(wv, xlg[j]);
                }
                #pragma unroll
                for (int off = 32; off >= 1; off >>= 1)
                    mud += __shfl_xor(mud, off, 64);
                if (lane == 0) {
                    float m1 = (float)mud;
                    m1 = __fadd_rn(m1, sbd[gg]);
                    m1 = __fadd_rn(m1, bias_b[0]);
                    muOut[row] = m1;
                }
            }
        }
        __syncthreads();
    }
}

extern "C" void kernel_launch(void* const* d_in, const int* in_sizes, int n_in,
                              void* d_out, int out_size, void* d_ws, size_t ws_size,
                              hipStream_t stream) {
    const float* x         = (const float*)d_in[0];
    const float* lag_embed = (const float*)d_in[1];
    const float* val_w     = (const float*)d_in[2];
    const float* val_b     = (const float*)d_in[3];
    const float* conv_w    = (const float*)d_in[4];
    const float* conv_b    = (const float*)d_in[5];
    const float* ctx_w     = (const float*)d_in[6];
    const float* ctx_b     = (const float*)d_in[7];
    const float* wq        = (const float*)d_in[8];
    const float* wk        = (const float*)d_in[9];
    const float* bias_w    = (const float*)d_in[10];
    const float* bias_b    = (const float*)d_in[11];

    double* wsd = (double*)d_ws;
    double* T2  = wsd;              // 16384
    double* g   = wsd + 16384;      // 1152
    double* u   = wsd + 17536;      // 128
    double* c1  = wsd + 17664;      // 128
    double* gbT = wsd + 17792;      // 2304
    double* cbv = wsd + 20096;      // 256
    double* cst = wsd + 20352;      // 20
    int* wcnt  = (int*)((char*)d_ws + 262144);
    int* wlist = wcnt + 1;          // WCAP entries

    float* muOut = (float*)d_out;
    float* wOut  = muOut + BQ * TQ;

    hipLaunchKernelGGL(pk1, dim3(D + 2), dim3(D), 0, stream, wk, wq, ctx_w, bias_w, T2, u, wcnt);
    hipLaunchKernelGGL(pk2, dim3(D), dim3(D), 0, stream, T2, ctx_w, conv_w, conv_b, ctx_b, g, c1);
    hipLaunchKernelGGL(pk3, dim3(LQ + 1), dim3(D), 0, stream,
                       lag_embed, val_b, val_w, conv_w, conv_b, ctx_b, bias_w, bias_b,
                       g, c1, u, gbT, cbv, cst);
    hipLaunchKernelGGL(lag_main, dim3(BQ * TQ / 4), dim3(256), 0, stream,
                       x, gbT, cbv, cst, muOut, wOut, wcnt, wlist);
    hipLaunchKernelGGL(fixer, dim3(256), dim3(256), 0, stream,
                       x, lag_embed, val_w, val_b, conv_w, conv_b, ctx_w, ctx_b,
                       wq, wk, bias_w, bias_b, wcnt, wlist, muOut, wOut);
}

// Round 5
// 129.746 us; speedup vs baseline: 3.8087x; 3.8087x over previous
//
#include <hip/hip_runtime.h>
#include <math.h>

#define D   128
#define LQ  256
#define KCQ 9
#define BQ  8
#define TQ  4096
#define RISK_DELTA 2e-5f
#define WCAP 65536

// ---------------- precompute kernels (weights-only, tiny, all-double) ----------------
__global__ void pk1(const float* __restrict__ wk, const float* __restrict__ wq,
                    const float* __restrict__ ctx_w, const float* __restrict__ bias_w,
                    double* __restrict__ T2, double* __restrict__ u, int* __restrict__ wcnt) {
    int e = threadIdx.x;
    if (blockIdx.x < D) {
        int d = blockIdx.x;
        double acc = 0.0;
        for (int j = 0; j < D; ++j)
            acc += (double)wk[j * D + d] * (double)wq[j * D + e];
        T2[d * D + e] = acc;
    } else if (blockIdx.x == D) {
        double acc = 0.0;
        for (int dd = 0; dd < D; ++dd)
            acc += (double)bias_w[dd] * (double)ctx_w[dd * D + e];
        u[e] = acc;
    } else {
        if (e == 0) *wcnt = 0;
    }
}

__global__ void pk2(const double* __restrict__ T2, const float* __restrict__ ctx_w,
                    const float* __restrict__ conv_w, const float* __restrict__ conv_b,
                    const float* __restrict__ ctx_b,
                    double* __restrict__ g, double* __restrict__ c1) {
    __shared__ double row[D];
    int d = blockIdx.x, e = threadIdx.x;
    double acc = 0.0;
    for (int j = 0; j < D; ++j)
        acc += T2[d * D + j] * (double)ctx_w[j * D + e];
    row[e] = acc;
    __syncthreads();
    if (e < KCQ) {
        double a = 0.0;
        for (int q = 0; q < D; ++q) a += row[q] * (double)conv_w[q * KCQ + e];
        g[e * D + d] = a;           // tap-major: g[k][d]
    } else if (e == KCQ) {
        double a = 0.0;
        for (int q = 0; q < D; ++q) a += row[q] * (double)conv_b[q];
        for (int q = 0; q < D; ++q) a += T2[d * D + q] * (double)ctx_b[q];
        c1[d] = a;
    }
}

__global__ void pk3(const float* __restrict__ lag_embed, const float* __restrict__ val_b,
                    const float* __restrict__ val_w, const float* __restrict__ conv_w,
                    const float* __restrict__ conv_b, const float* __restrict__ ctx_b,
                    const float* __restrict__ bias_w, const float* __restrict__ bias_b,
                    const double* __restrict__ g, const double* __restrict__ c1,
                    const double* __restrict__ u,
                    double* __restrict__ gbT, double* __restrict__ cbv, double* __restrict__ cst) {
    int tid = threadIdx.x;
    if (blockIdx.x < LQ) {
        __shared__ double bl[D];
        int l = blockIdx.x;
        bl[tid] = (double)val_b[tid] + (double)lag_embed[(l + 1) * D + tid];
        __syncthreads();
        if (tid < KCQ) {
            double a = 0.0;
            for (int q = 0; q < D; ++q) a += bl[q] * g[tid * D + q];
            gbT[tid * LQ + l] = a;
        } else if (tid == KCQ) {
            double a = 0.0;
            for (int q = 0; q < D; ++q) a += bl[q] * c1[q];
            cbv[l] = a;
        }
    } else {
        if (tid < KCQ) {
            double a = 0.0, a2 = 0.0;
            for (int q = 0; q < D; ++q) a  += g[tid * D + q] * (double)val_w[q];
            for (int q = 0; q < D; ++q) a2 += u[q] * (double)conv_w[q * KCQ + tid];
            cst[tid]      = a;    // sk[k]
            cst[10 + tid] = a2;   // hk[k]
        } else if (tid == KCQ) {
            double a = 0.0, a2 = 0.0;
            for (int q = 0; q < D; ++q) a  += c1[q] * (double)val_w[q];
            for (int q = 0; q < D; ++q) a2 += u[q] * (double)conv_b[q];
            for (int q = 0; q < D; ++q) a2 += (double)bias_w[q] * (double)ctx_b[q];
            cst[9]  = a;                          // ssc
            cst[19] = a2 + (double)bias_b[0];     // hc (incl. bias_b)
        }
    }
}

// ---------------- main kernel: all-f32, near-tie rows deferred to fixer ----------
// Lane owns l = l0..l0+3 (l0 = lane*4): float4 LDS reads + float4 w stores.
__global__ __launch_bounds__(256, 4) void lag_main(
    const float* __restrict__ x, const double* __restrict__ gbT,
    const double* __restrict__ cbv, const double* __restrict__ cst,
    float* __restrict__ muOut, float* __restrict__ wOut,
    int* __restrict__ wcnt, int* __restrict__ wlist) {
    __shared__ float sgb[KCQ * LQ];
    __shared__ float scb[LQ];
    __shared__ float sc[20];
    int tid = threadIdx.x;
    #pragma unroll
    for (int i = 0; i < KCQ; ++i) sgb[i * LQ + tid] = (float)gbT[i * LQ + tid];
    scb[tid] = (float)cbv[tid];
    if (tid < 20) sc[tid] = (float)cst[tid];
    __syncthreads();

    int wave = tid >> 6, lane = tid & 63;
    int row = blockIdx.x * 4 + wave;
    int b = row >> 12;
    int t = row & (TQ - 1);
    const float* xb = x + b * TQ;

    float xw[KCQ];
    #pragma unroll
    for (int k = 0; k < KCQ; ++k) {
        int idx = t - 8 + k;
        xw[k] = (idx >= 0) ? xb[idx] : 0.f;
    }
    float s = sc[9], bias = sc[19];
    #pragma unroll
    for (int k = 0; k < KCQ; ++k) {
        s    = fmaf(sc[k],      xw[k], s);
        bias = fmaf(sc[10 + k], xw[k], bias);
    }

    int l0 = lane * 4;
    float xlag[4];
    #pragma unroll
    for (int i = 0; i < 4; ++i) {
        int idx = t - 1 - (l0 + i);
        xlag[i] = (idx >= 0) ? xb[idx] : 0.f;
    }

    float4 cb4 = *reinterpret_cast<const float4*>(&scb[l0]);
    float lg[4] = {cb4.x, cb4.y, cb4.z, cb4.w};
    #pragma unroll
    for (int k = 0; k < KCQ; ++k) {
        float4 g4 = *reinterpret_cast<const float4*>(&sgb[k * LQ + l0]);
        lg[0] = fmaf(g4.x, xw[k], lg[0]);
        lg[1] = fmaf(g4.y, xw[k], lg[1]);
        lg[2] = fmaf(g4.z, xw[k], lg[2]);
        lg[3] = fmaf(g4.w, xw[k], lg[3]);
    }
    #pragma unroll
    for (int i = 0; i < 4; ++i) lg[i] = fmaf(xlag[i], s, lg[i]);

    // top-9 extraction (f32): v1 (mx), v8 (thr), v9 (risk gap)
    const float NEG_INF = -__builtin_inff();
    float wl0 = lg[0], wl1 = lg[1], wl2 = lg[2], wl3 = lg[3];
    float mx = 0.f, thr = 0.f, v9 = 0.f;
    #pragma unroll
    for (int it = 0; it < 9; ++it) {
        float lm = fmaxf(fmaxf(wl0, wl1), fmaxf(wl2, wl3));
        float m = lm;
        #pragma unroll
        for (int off = 32; off >= 1; off >>= 1)
            m = fmaxf(m, __shfl_xor(m, off, 64));
        if (it == 0) mx = m;
        if (it == 7) thr = m;
        if (it == 8) v9 = m;
        if (it < 8) {
            unsigned long long ball = __ballot(lm == m);
            int leader = __ffsll(ball) - 1;
            if (lane == leader) {
                if (wl0 == m)      wl0 = NEG_INF;
                else if (wl1 == m) wl1 = NEG_INF;
                else if (wl2 == m) wl2 = NEG_INF;
                else               wl3 = NEG_INF;
            }
        }
    }

    if ((thr - v9) < RISK_DELTA) {
        if (lane == 0) {
            int pos = atomicAdd(wcnt, 1);
            if (pos < WCAP) wlist[pos] = row;
        }
        return;
    }

    float p[4], psum = 0.f, pmu = 0.f;
    #pragma unroll
    for (int j = 0; j < 4; ++j) {
        p[j] = (lg[j] >= thr) ? __expf(lg[j] - mx) : 0.f;
        psum += p[j];
        pmu = fmaf(p[j], xlag[j], pmu);
    }
    #pragma unroll
    for (int off = 32; off >= 1; off >>= 1) {
        psum += __shfl_xor(psum, off, 64);
        pmu  += __shfl_xor(pmu,  off, 64);
    }
    float inv = 1.f / psum;
    float4 wo = make_float4(p[0] * inv, p[1] * inv, p[2] * inv, p[3] * inv);
    *reinterpret_cast<float4*>(&wOut[(size_t)row * LQ + l0]) = wo;
    if (lane == 0) muOut[row] = fmaf(pmu, inv, bias);
}

// ---------------- fixer: np-faithful fp32 pipeline (sequential f32 FMA dots) --------
// PROVEN arbiter-matcher in round 4 — arithmetic unchanged.
__global__ __launch_bounds__(256) void fixer(
    const float* __restrict__ x, const float* __restrict__ lag_embed,
    const float* __restrict__ val_w, const float* __restrict__ val_b,
    const float* __restrict__ conv_w, const float* __restrict__ conv_b,
    const float* __restrict__ ctx_w, const float* __restrict__ ctx_b,
    const float* __restrict__ wq, const float* __restrict__ wk,
    const float* __restrict__ bias_w, const float* __restrict__ bias_b,
    const int* __restrict__ wcnt, const int* __restrict__ wlist,
    float* __restrict__ muOut, float* __restrict__ wOut) {
    __shared__ float sxw[8][KCQ];
    __shared__ float sctxc[8][D];
    __shared__ float sctxp[8][D];
    __shared__ float sq[8][D];
    __shared__ float sqk[8][D];
    __shared__ float ssv[8];
    __shared__ float sbd[8];
    __shared__ float slog[8][LQ];
    __shared__ int   srow[8];

    int cnt = *wcnt;
    if (cnt > WCAP) cnt = WCAP;
    int ngroups = (cnt + 7) >> 3;
    int tid = threadIdx.x;

    for (int gi = blockIdx.x; gi < ngroups; gi += gridDim.x) {
        if (tid < 8) {
            int idx = gi * 8 + tid;
            if (idx >= cnt) idx = cnt - 1;   // pad with last row (duplicate write is benign)
            srow[tid] = wlist[idx];
        }
        __syncthreads();
        if (tid < 8 * KCQ) {
            int g = tid / KCQ, k = tid % KCQ;
            int row = srow[g]; int b = row >> 12, t = row & (TQ - 1);
            int ii = t - 8 + k;
            sxw[g][k] = (ii >= 0) ? x[b * TQ + ii] : 0.f;
        }
        __syncthreads();

        // stage 1: causal conv — sequential f32 FMA over k, then f32 add of conv_b
        {
            int d = tid & (D - 1), gh = tid >> 7;
            for (int g = gh * 4; g < gh * 4 + 4; ++g) {
                float a = 0.f;
                #pragma unroll
                for (int k = 0; k < KCQ; ++k)
                    a = fmaf(conv_w[d * KCQ + k], sxw[g][k], a);
                sctxc[g][d] = __fadd_rn(a, conv_b[d]);
            }
        }
        __syncthreads();

        // stage 2: ctx_proj — sequential f32 FMA over d, then + ctx_b
        {
            int e = tid & (D - 1), gh = tid >> 7, g0 = gh * 4;
            float a0 = 0.f, a1 = 0.f, a2 = 0.f, a3 = 0.f;
            for (int d2 = 0; d2 < D; ++d2) {
                float wv = ctx_w[e * D + d2];
                a0 = fmaf(wv, sctxc[g0 + 0][d2], a0);
                a1 = fmaf(wv, sctxc[g0 + 1][d2], a1);
                a2 = fmaf(wv, sctxc[g0 + 2][d2], a2);
                a3 = fmaf(wv, sctxc[g0 + 3][d2], a3);
            }
            float cb = ctx_b[e];
            sctxp[g0 + 0][e] = __fadd_rn(a0, cb);
            sctxp[g0 + 1][e] = __fadd_rn(a1, cb);
            sctxp[g0 + 2][e] = __fadd_rn(a2, cb);
            sctxp[g0 + 3][e] = __fadd_rn(a3, cb);
        }
        __syncthreads();

        // stage 3: q = ctx @ wq.T — sequential f32 FMA over e
        {
            int a = tid & (D - 1), gh = tid >> 7, g0 = gh * 4;
            float a0 = 0.f, a1 = 0.f, a2 = 0.f, a3 = 0.f;
            for (int e2 = 0; e2 < D; ++e2) {
                float wv = wq[a * D + e2];
                a0 = fmaf(wv, sctxp[g0 + 0][e2], a0);
                a1 = fmaf(wv, sctxp[g0 + 1][e2], a1);
                a2 = fmaf(wv, sctxp[g0 + 2][e2], a2);
                a3 = fmaf(wv, sctxp[g0 + 3][e2], a3);
            }
            sq[g0 + 0][a] = a0;
            sq[g0 + 1][a] = a1;
            sq[g0 + 2][a] = a2;
            sq[g0 + 3][a] = a3;
        }
        __syncthreads();

        // stage 4: qk = q @ wk — sequential f32 FMA over a
        {
            int d = tid & (D - 1), gh = tid >> 7, g0 = gh * 4;
            float a0 = 0.f, a1 = 0.f, a2 = 0.f, a3 = 0.f;
            for (int a2i = 0; a2i < D; ++a2i) {
                float wv = wk[a2i * D + d];
                a0 = fmaf(wv, sq[g0 + 0][a2i], a0);
                a1 = fmaf(wv, sq[g0 + 1][a2i], a1);
                a2 = fmaf(wv, sq[g0 + 2][a2i], a2);
                a3 = fmaf(wv, sq[g0 + 3][a2i], a3);
            }
            sqk[g0 + 0][d] = a0;
            sqk[g0 + 1][d] = a1;
            sqk[g0 + 2][d] = a2;
            sqk[g0 + 3][d] = a3;
        }
        __syncthreads();

        // s = qk·val_w ; biasdot = ctxp·bias_w — sequential f32 FMA
        if (tid < 8) {
            int g = tid;
            float a = 0.f;
            for (int d2 = 0; d2 < D; ++d2) a = fmaf(sqk[g][d2], val_w[d2], a);
            ssv[g] = a;
        } else if (tid < 16) {
            int g = tid - 8;
            float a = 0.f;
            for (int e2 = 0; e2 < D; ++e2) a = fmaf(sctxp[g][e2], bias_w[e2], a);
            sbd[g] = a;
        }
        __syncthreads();

        // logits: blog[l] = Σ_d f32(val_b+le)·qk[d] sequential f32 FMA;
        // logit = f32(xlag*s) + blog (separate f32 mul/add, like numpy elementwise)
        {
            int l = tid;
            float c0 = 0.f, c1a = 0.f, c2 = 0.f, c3 = 0.f, c4 = 0.f, c5 = 0.f, c6 = 0.f, c7 = 0.f;
            const float* le = lag_embed + (size_t)(l + 1) * D;
            for (int d2 = 0; d2 < D; ++d2) {
                float bd = __fadd_rn(val_b[d2], le[d2]);
                c0 = fmaf(bd, sqk[0][d2], c0);
                c1a = fmaf(bd, sqk[1][d2], c1a);
                c2 = fmaf(bd, sqk[2][d2], c2);
                c3 = fmaf(bd, sqk[3][d2], c3);
                c4 = fmaf(bd, sqk[4][d2], c4);
                c5 = fmaf(bd, sqk[5][d2], c5);
                c6 = fmaf(bd, sqk[6][d2], c6);
                c7 = fmaf(bd, sqk[7][d2], c7);
            }
            float accs[8] = {c0, c1a, c2, c3, c4, c5, c6, c7};
            #pragma unroll
            for (int g = 0; g < 8; ++g) {
                int row = srow[g]; int b = row >> 12, t = row & (TQ - 1);
                int ii = t - 1 - l;
                float xl = (ii >= 0) ? x[b * TQ + ii] : 0.f;
                slog[g][l] = __fadd_rn(__fmul_rn(xl, ssv[g]), accs[g]);
            }
        }
        __syncthreads();

        // per-row f32 top-8 + f32 softmax + writes; wave handles 2 rows
        {
            int wave = tid >> 6, lane = tid & 63;
            for (int gg = wave * 2; gg < wave * 2 + 2; ++gg) {
                float lv0 = slog[gg][lane], lv1 = slog[gg][lane + 64];
                float lv2 = slog[gg][lane + 128], lv3 = slog[gg][lane + 192];
                const float NEG_INF = -__builtin_inff();
                float w0 = lv0, w1 = lv1, w2 = lv2, w3 = lv3;
                float mx = 0.f, thr = 0.f;
                #pragma unroll
                for (int it = 0; it < 8; ++it) {
                    float lm = fmaxf(fmaxf(w0, w1), fmaxf(w2, w3));
                    float m = lm;
                    #pragma unroll
                    for (int off = 32; off >= 1; off >>= 1)
                        m = fmaxf(m, __shfl_xor(m, off, 64));
                    if (it == 0) mx = m;
                    thr = m;
                    if (it < 7) {
                        unsigned long long ball = __ballot(lm == m);
                        int leader = __ffsll(ball) - 1;
                        if (lane == leader) {
                            if (w0 == m)      w0 = NEG_INF;
                            else if (w1 == m) w1 = NEG_INF;
                            else if (w2 == m) w2 = NEG_INF;
                            else              w3 = NEG_INF;
                        }
                    }
                }
                int row = srow[gg]; int b = row >> 12, t = row & (TQ - 1);
                float p[4], xlg[4];
                double ps = 0.0;
                float lvs[4] = {lv0, lv1, lv2, lv3};
                #pragma unroll
                for (int j = 0; j < 4; ++j) {
                    int l = lane + 64 * j;
                    int ii = t - 1 - l;
                    xlg[j] = (ii >= 0) ? x[b * TQ + ii] : 0.f;
                    p[j] = (lvs[j] >= thr) ? (float)exp((double)__fsub_rn(lvs[j], mx)) : 0.f;
                    ps += (double)p[j];
                }
                #pragma unroll
                for (int off = 32; off >= 1; off >>= 1)
                    ps += __shfl_xor(ps, off, 64);
                float psf = (float)ps;
                double mud = 0.0;
                #pragma unroll
                for (int j = 0; j < 4; ++j) {
                    float wv = __fdiv_rn(p[j], psf);
                    wOut[(size_t)row * LQ + lane + 64 * j] = wv;
                    mud += (double)__fmul_rn(wv, xlg[j]);
                }
                #pragma unroll
                for (int off = 32; off >= 1; off >>= 1)
                    mud += __shfl_xor(mud, off, 64);
                if (lane == 0) {
                    float m1 = (float)mud;
                    m1 = __fadd_rn(m1, sbd[gg]);
                    m1 = __fadd_rn(m1, bias_b[0]);
                    muOut[row] = m1;
                }
            }
        }
        __syncthreads();
    }
}

extern "C" void kernel_launch(void* const* d_in, const int* in_sizes, int n_in,
                              void* d_out, int out_size, void* d_ws, size_t ws_size,
                              hipStream_t stream) {
    const float* x         = (const float*)d_in[0];
    const float* lag_embed = (const float*)d_in[1];
    const float* val_w     = (const float*)d_in[2];
    const float* val_b     = (const float*)d_in[3];
    const float* conv_w    = (const float*)d_in[4];
    const float* conv_b    = (const float*)d_in[5];
    const float* ctx_w     = (const float*)d_in[6];
    const float* ctx_b     = (const float*)d_in[7];
    const float* wq        = (const float*)d_in[8];
    const float* wk        = (const float*)d_in[9];
    const float* bias_w    = (const float*)d_in[10];
    const float* bias_b    = (const float*)d_in[11];

    double* wsd = (double*)d_ws;
    double* T2  = wsd;              // 16384
    double* g   = wsd + 16384;      // 1152
    double* u   = wsd + 17536;      // 128
    double* c1  = wsd + 17664;      // 128
    double* gbT = wsd + 17792;      // 2304
    double* cbv = wsd + 20096;      // 256
    double* cst = wsd + 20352;      // 20
    int* wcnt  = (int*)((char*)d_ws + 262144);
    int* wlist = wcnt + 1;          // WCAP entries

    float* muOut = (float*)d_out;
    float* wOut  = muOut + BQ * TQ;

    hipLaunchKernelGGL(pk1, dim3(D + 2), dim3(D), 0, stream, wk, wq, ctx_w, bias_w, T2, u, wcnt);
    hipLaunchKernelGGL(pk2, dim3(D), dim3(D), 0, stream, T2, ctx_w, conv_w, conv_b, ctx_b, g, c1);
    hipLaunchKernelGGL(pk3, dim3(LQ + 1), dim3(D), 0, stream,
                       lag_embed, val_b, val_w, conv_w, conv_b, ctx_b, bias_w, bias_b,
                       g, c1, u, gbT, cbv, cst);
    hipLaunchKernelGGL(lag_main, dim3(BQ * TQ / 4), dim3(256), 0, stream,
                       x, gbT, cbv, cst, muOut, wOut, wcnt, wlist);
    hipLaunchKernelGGL(fixer, dim3(256), dim3(256), 0, stream,
                       x, lag_embed, val_w, val_b, conv_w, conv_b, ctx_w, ctx_b,
                       wq, wk, bias_w, bias_b, wcnt, wlist, muOut, wOut);
}